// Round 1
// baseline (135.371 us; speedup 1.0000x reference)
//
#include <hip/hip_runtime.h>

#define LARGEF 1e9f

constexpr int BLOCK = 256;
constexpr int OPT   = 8;                  // outputs per thread
constexpr int TILE  = BLOCK * OPT;        // 2048 outputs per block
constexpr int MAXB  = 255;                // fast path supports b <= MAXB
constexpr int LDSN  = TILE + MAXB;        // max staged positions = TILE + b
constexpr int LDSPAD = LDSN + (LDSN >> 5) + 8;

__device__ __forceinline__ int phys(int i) { return i + (i >> 5); }

__global__ __launch_bounds__(BLOCK)
void until_kernel(const float* __restrict__ s1, const float* __restrict__ s2,
                  const int* __restrict__ pa, const int* __restrict__ pb,
                  float* __restrict__ out, int T)
{
    const int a = pa[0];
    const int b = pb[0];
    const long base = (long)blockIdx.x * TILE;

    __shared__ float l1[LDSPAD];
    __shared__ float l2[LDSPAD];

    if (b >= 0 && b <= MAXB) {
        // ---- stage tile into LDS (clamped = 'last' padding) ----
        const int n = TILE + b;  // positions base .. base+TILE-1+b
        for (int i = threadIdx.x; i < n; i += BLOCK) {
            long g = base + i;
            if (g > (long)T - 1) g = (long)T - 1;
            l1[phys(i)] = s1[g];
            l2[phys(i)] = s2[g];
        }
        __syncthreads();

        const int j0 = (int)threadIdx.x * OPT;
        float m[OPT], o[OPT];
        #pragma unroll
        for (int r = 0; r < OPT; ++r) { m[r] = LARGEF; o[r] = -LARGEF; }

        if (a == 0 && b >= OPT - 1) {
            // head: k in [0, OPT-2], only r <= k active (d = k-r in [0,k] <= b)
            #pragma unroll
            for (int k = 0; k < OPT - 1; ++k) {
                const float v1 = l1[phys(j0 + k)];
                const float v2 = l2[phys(j0 + k)];
                #pragma unroll
                for (int r = 0; r < OPT; ++r) {
                    if (r <= k) {
                        m[r] = fminf(m[r], v1);
                        o[r] = fmaxf(o[r], fminf(m[r], v2));
                    }
                }
            }
            // body: k in [OPT-1, b], all 8 outputs active, unpredicated
            for (int k = OPT - 1; k <= b; ++k) {
                const float v1 = l1[phys(j0 + k)];
                const float v2 = l2[phys(j0 + k)];
                #pragma unroll
                for (int r = 0; r < OPT; ++r) {
                    m[r] = fminf(m[r], v1);
                    o[r] = fmaxf(o[r], fminf(m[r], v2));
                }
            }
            // tail: k in [b+1, b+OPT-1], only r >= k-b active
            #pragma unroll
            for (int kt = 1; kt < OPT; ++kt) {
                const int k = b + kt;
                const float v1 = l1[phys(j0 + k)];
                const float v2 = l2[phys(j0 + k)];
                #pragma unroll
                for (int r = 0; r < OPT; ++r) {
                    if (r >= kt) {
                        m[r] = fminf(m[r], v1);
                        o[r] = fmaxf(o[r], fminf(m[r], v2));
                    }
                }
            }
        } else {
            // generic predicated path (a != 0 or b < 7), still LDS-staged
            for (int k = 0; k <= b + OPT - 1; ++k) {
                const float v1 = l1[phys(j0 + k)];
                const float v2 = l2[phys(j0 + k)];
                #pragma unroll
                for (int r = 0; r < OPT; ++r) {
                    const int d = k - r;
                    if (d >= 0 && d <= b) {
                        m[r] = fminf(m[r], v1);
                        if (d >= a) o[r] = fmaxf(o[r], fminf(m[r], v2));
                    }
                }
            }
        }

        // ---- store 8 consecutive outputs (two float4) ----
        const long jg = base + j0;
        if (jg + OPT <= (long)T) {
            float4* p = (float4*)(out + jg);
            p[0] = make_float4(o[0], o[1], o[2], o[3]);
            p[1] = make_float4(o[4], o[5], o[6], o[7]);
        } else {
            for (int r = 0; r < OPT; ++r)
                if (jg + r < (long)T) out[jg + r] = o[r];
        }
    } else {
        // ---- slow generic fallback (b > MAXB): direct global loads ----
        const long j0 = base + (long)threadIdx.x * OPT;
        float m[OPT], o[OPT];
        #pragma unroll
        for (int r = 0; r < OPT; ++r) { m[r] = LARGEF; o[r] = -LARGEF; }
        const long kend = (long)b + OPT - 1;
        for (long k = 0; k <= kend; ++k) {
            long g = j0 + k;
            if (g > (long)T - 1) g = (long)T - 1;
            if (g < 0) g = 0;
            const float v1 = s1[g];
            const float v2 = s2[g];
            #pragma unroll
            for (int r = 0; r < OPT; ++r) {
                const long d = k - r;
                if (d >= 0 && d <= (long)b) {
                    m[r] = fminf(m[r], v1);
                    if (d >= (long)a) o[r] = fmaxf(o[r], fminf(m[r], v2));
                }
            }
        }
        for (int r = 0; r < OPT; ++r)
            if (j0 + r < (long)T) out[j0 + r] = o[r];
    }
}

extern "C" void kernel_launch(void* const* d_in, const int* in_sizes, int n_in,
                              void* d_out, int out_size, void* d_ws, size_t ws_size,
                              hipStream_t stream) {
    const float* s1 = (const float*)d_in[0];
    const float* s2 = (const float*)d_in[1];
    const int*   pa = (const int*)d_in[2];
    const int*   pb = (const int*)d_in[3];
    float* out = (float*)d_out;
    const int T = in_sizes[0];

    const int nblk = (T + TILE - 1) / TILE;
    until_kernel<<<nblk, BLOCK, 0, stream>>>(s1, s2, pa, pb, out, T);
}

// Round 3
// 89.860 us; speedup vs baseline: 1.5065x; 1.5065x over previous
//
#include <hip/hip_runtime.h>

#define LARGEF 1e9f
#define FINF   3.0e38f

constexpr int BLOCK = 256;
constexpr int OPT   = 8;                  // outputs per thread
constexpr int TILE  = BLOCK * OPT;        // 2048 outputs per block
constexpr int MAXB  = 255;                // LDS paths support b <= MAXB
constexpr int MAXCH = (TILE + MAXB + 31) >> 5;   // 72 chunks max
constexpr int STR   = 36;                 // padded chunk stride (floats), 144B = 16B aligned
constexpr int LDSF  = MAXCH * STR;        // 2592 floats per array

__device__ __forceinline__ int pidx(int i) { return (i >> 5) * STR + (i & 31); }

__global__ __launch_bounds__(BLOCK)
void until_kernel(const float* __restrict__ s1, const float* __restrict__ s2,
                  const int* __restrict__ pa, const int* __restrict__ pb,
                  float* __restrict__ out, int T)
{
    const int a = pa[0];
    const int b = pb[0];
    const long base = (long)blockIdx.x * TILE;

    __shared__ float l1[LDSF];   // s1 -> (pass B) suffix-min within chunk
    __shared__ float l2[LDSF];   // s2 -> (pass B) suffix-until within chunk
    __shared__ float cm[LDSF];   // (pass A) prefix-max of min(prefmin(s1), s2) within chunk

    if (b >= 0 && b <= MAXB) {
        const int nch = (TILE + b + 31) >> 5;
        const int Ns  = nch << 5;            // staged positions (chunk-padded)

        // ---- stage tile into LDS ('last' padding via clamp) ----
        if (base + Ns <= (long)T) {
            for (int i4 = (int)threadIdx.x * 4; i4 < Ns; i4 += BLOCK * 4) {
                float4 u = *(const float4*)(s1 + base + i4);
                float4 v = *(const float4*)(s2 + base + i4);
                *(float4*)&l1[pidx(i4)] = u;
                *(float4*)&l2[pidx(i4)] = v;
            }
        } else {
            for (int i = threadIdx.x; i < Ns; i += BLOCK) {
                long g = base + i; if (g > (long)T - 1) g = (long)T - 1;
                l1[pidx(i)] = s1[g];
                l2[pidx(i)] = s2[g];
            }
        }
        __syncthreads();

        if (a == 0 && b >= 32) {
            // ---- per-chunk scans (thread c owns chunk c) ----
            if ((int)threadIdx.x < nch) {
                const int cb = (int)threadIdx.x * STR;
                // pass A (forward): cm[t] = max_{u<=t in chunk} min( min s1[chunk..u], s2[u] )
                float p = FINF, rm = -FINF;
                #pragma unroll
                for (int q = 0; q < 8; ++q) {
                    float4 u = *(float4*)&l1[cb + q * 4];
                    float4 v = *(float4*)&l2[cb + q * 4];
                    float4 w;
                    p = fminf(p, u.x); rm = fmaxf(rm, fminf(p, v.x)); w.x = rm;
                    p = fminf(p, u.y); rm = fmaxf(rm, fminf(p, v.y)); w.y = rm;
                    p = fminf(p, u.z); rm = fmaxf(rm, fminf(p, v.z)); w.z = rm;
                    p = fminf(p, u.w); rm = fmaxf(rm, fminf(p, v.w)); w.w = rm;
                    *(float4*)&cm[cb + q * 4] = w;
                }
                // pass B (backward): sm over l1, sf over l2
                //   sm[t] = min s1[t..chunkend];  sf[t] = max_{u in [t,chunkend]} min(min s1[t..u], s2[u])
                //   recurrence: sf = min(v1, max(v2, sf_next))
                float smn = FINF, sfn = -FINF;
                #pragma unroll
                for (int q = 7; q >= 0; --q) {
                    float4 u = *(float4*)&l1[cb + q * 4];
                    float4 v = *(float4*)&l2[cb + q * 4];
                    float4 sm4, sf4;
                    sfn = fminf(u.w, fmaxf(v.w, sfn)); sf4.w = sfn;  smn = fminf(u.w, smn); sm4.w = smn;
                    sfn = fminf(u.z, fmaxf(v.z, sfn)); sf4.z = sfn;  smn = fminf(u.z, smn); sm4.z = smn;
                    sfn = fminf(u.y, fmaxf(v.y, sfn)); sf4.y = sfn;  smn = fminf(u.y, smn); sm4.y = smn;
                    sfn = fminf(u.x, fmaxf(v.x, sfn)); sf4.x = sfn;  smn = fminf(u.x, smn); sm4.x = smn;
                    *(float4*)&l1[cb + q * 4] = sm4;
                    *(float4*)&l2[cb + q * 4] = sf4;
                }
            }
            __syncthreads();

            // ---- main pass: l1 = sufmin, l2 = suf, cm = chunk prefix-until-max ----
            const int jl = (int)threadIdx.x * OPT;
            const int c0 = jl >> 5;
            const int e0 = jl + b;
            const int Gm = e0 >> 5;

            float o[OPT], x[OPT];
            {
                float4 sA = *(float4*)&l2[pidx(jl)];
                float4 sB = *(float4*)&l2[pidx(jl + 4)];
                float4 mA = *(float4*)&l1[pidx(jl)];
                float4 mB = *(float4*)&l1[pidx(jl + 4)];
                o[0]=sA.x; o[1]=sA.y; o[2]=sA.z; o[3]=sA.w;
                o[4]=sB.x; o[5]=sB.y; o[6]=sB.z; o[7]=sB.w;
                x[0]=mA.x; x[1]=mA.y; x[2]=mA.z; x[3]=mA.w;
                x[4]=mB.x; x[5]=mB.y; x[6]=mB.z; x[7]=mB.w;
            }
            // full chunks shared by all 8 outputs
            for (int g = c0 + 1; g < Gm; ++g) {
                const float GV = cm[g * STR + 31];
                const float WV = l1[g * STR];
                #pragma unroll
                for (int r = 0; r < OPT; ++r) {
                    o[r] = fmaxf(o[r], fminf(x[r], GV));
                    x[r] = fminf(x[r], WV);
                }
            }
            // boundary chunk Gm: full for outputs whose window end crosses into Gm+1
            {
                const float GV = cm[Gm * STR + 31];
                const float WV = l1[Gm * STR];
                const int lim = (Gm + 1) << 5;
                #pragma unroll
                for (int r = 0; r < OPT; ++r) {
                    const int e = e0 + r;
                    if (e >= lim) {
                        o[r] = fmaxf(o[r], fminf(x[r], GV));
                        x[r] = fminf(x[r], WV);
                    }
                    o[r] = fmaxf(o[r], fminf(x[r], cm[pidx(e)]));
                }
            }
            // ---- store ----
            const long jg = base + jl;
            if (jg + OPT <= (long)T) {
                *(float4*)(out + jg)     = make_float4(o[0], o[1], o[2], o[3]);
                *(float4*)(out + jg + 4) = make_float4(o[4], o[5], o[6], o[7]);
            } else {
                for (int r = 0; r < OPT; ++r)
                    if (jg + r < (long)T) out[jg + r] = o[r];
            }
        } else {
            // ---- generic predicated LDS path (a != 0 or b < 32) ----
            const int j0 = (int)threadIdx.x * OPT;
            float m[OPT], o[OPT];
            #pragma unroll
            for (int r = 0; r < OPT; ++r) { m[r] = LARGEF; o[r] = -LARGEF; }
            for (int k = 0; k <= b + OPT - 1; ++k) {
                const float v1 = l1[pidx(j0 + k)];
                const float v2 = l2[pidx(j0 + k)];
                #pragma unroll
                for (int r = 0; r < OPT; ++r) {
                    const int d = k - r;
                    if (d >= 0 && d <= b) {
                        m[r] = fminf(m[r], v1);
                        if (d >= a) o[r] = fmaxf(o[r], fminf(m[r], v2));
                    }
                }
            }
            const long jg = base + j0;
            if (jg + OPT <= (long)T) {
                *(float4*)(out + jg)     = make_float4(o[0], o[1], o[2], o[3]);
                *(float4*)(out + jg + 4) = make_float4(o[4], o[5], o[6], o[7]);
            } else {
                for (int r = 0; r < OPT; ++r)
                    if (jg + r < (long)T) out[jg + r] = o[r];
            }
        }
    } else {
        // ---- slow generic fallback (b > MAXB): direct global loads ----
        const long j0 = base + (long)threadIdx.x * OPT;
        float m[OPT], o[OPT];
        #pragma unroll
        for (int r = 0; r < OPT; ++r) { m[r] = LARGEF; o[r] = -LARGEF; }
        const long kend = (long)b + OPT - 1;
        for (long k = 0; k <= kend; ++k) {
            long g = j0 + k;
            if (g > (long)T - 1) g = (long)T - 1;
            if (g < 0) g = 0;
            const float v1 = s1[g];
            const float v2 = s2[g];
            #pragma unroll
            for (int r = 0; r < OPT; ++r) {
                const long d = k - r;
                if (d >= 0 && d <= (long)b) {
                    m[r] = fminf(m[r], v1);
                    if (d >= (long)a) o[r] = fmaxf(o[r], fminf(m[r], v2));
                }
            }
        }
        for (int r = 0; r < OPT; ++r)
            if (j0 + r < (long)T) out[j0 + r] = o[r];
    }
}

extern "C" void kernel_launch(void* const* d_in, const int* in_sizes, int n_in,
                              void* d_out, int out_size, void* d_ws, size_t ws_size,
                              hipStream_t stream) {
    const float* s1 = (const float*)d_in[0];
    const float* s2 = (const float*)d_in[1];
    const int*   pa = (const int*)d_in[2];
    const int*   pb = (const int*)d_in[3];
    float* out = (float*)d_out;
    const int T = in_sizes[0];

    const int nblk = (T + TILE - 1) / TILE;
    until_kernel<<<nblk, BLOCK, 0, stream>>>(s1, s2, pa, pb, out, T);
}